// Round 14
// baseline (200.575 us; speedup 1.0000x reference)
//
#include <hip/hip_runtime.h>

#define D 128
#define SCAN_B 1024

static inline int ceil_div_ll(long long a, int b) { return (int)((a + b - 1) / b); }

typedef unsigned int uint32;
typedef __attribute__((ext_vector_type(8))) short short8;   // 8 x bf16 (4 VGPRs)
typedef __attribute__((ext_vector_type(4))) float f32x4;    // MFMA C/D

__device__ __forceinline__ float blo(uint32 u) { return __uint_as_float(u << 16); }
__device__ __forceinline__ float bhi(uint32 u) { return __uint_as_float(u & 0xffff0000u); }
__device__ __forceinline__ uint32 bpack(float a, float b) {   // 2x f32 -> bf16x2 RTNE
    uint32 ua = __float_as_uint(a), ub = __float_as_uint(b);
    ua += 0x7fffu + ((ua >> 16) & 1u);
    ub += 0x7fffu + ((ub >> 16) & 1u);
    return (ua >> 16) | (ub & 0xffff0000u);
}

// FUSED: [0,ncount): packed degree histogram + per-edge row-rank emit
//        [ncount,+8): W -> MFMA B-fragment repack
__global__ __launch_bounds__(256) void k_fused(
        const int2* __restrict__ rows2, const int2* __restrict__ cols2,
        uint32* __restrict__ cnt, ushort* __restrict__ rank16, int E2, int odd,
        const int* __restrict__ rows, const int* __restrict__ cols,
        const float* __restrict__ Wm, uint4* __restrict__ wfrag, int ncount) {
    const int b = blockIdx.x;
    if (b < ncount) {
        const int t = b * 256 + threadIdx.x;
        if (t < E2) {
            const int2 r2 = rows2[t];
            const int2 c2 = cols2[t];
            const uint32 o0 = atomicAdd(&cnt[r2.x], 0x10000u);
            atomicAdd(&cnt[c2.x], 1u);
            const uint32 o1 = atomicAdd(&cnt[r2.y], 0x10000u);
            atomicAdd(&cnt[c2.y], 1u);
            ushort2 rk;
            rk.x = (ushort)(o0 >> 16);
            rk.y = (ushort)(o1 >> 16);
            *(ushort2*)(rank16 + 2 * t) = rk;
        } else if (t == E2 && odd) {
            const uint32 o = atomicAdd(&cnt[rows[2 * E2]], 0x10000u);
            atomicAdd(&cnt[cols[2 * E2]], 1u);
            rank16[2 * E2] = (ushort)(o >> 16);
        }
    } else {
        // wprep: lane l of entry (kq*8+jt) holds W[jt*16+(l&15)][kq*32+(l>>4)*8..+7]
        const int t = (b - ncount) * 256 + threadIdx.x;
        if (t >= 2048) return;
        const int l = t & 63;
        const int pair = t >> 6;
        const int kq = pair >> 3;
        const int jt = pair & 7;
        const int s = l & 15;
        const int g = l >> 4;
        const float* src = Wm + ((long long)(jt * 16 + s) << 7) + kq * 32 + g * 8;
        const float4 w0 = *(const float4*)(src);
        const float4 w1 = *(const float4*)(src + 4);
        uint4 o;
        o.x = bpack(w0.x, w0.y); o.y = bpack(w0.z, w0.w);
        o.z = bpack(w1.x, w1.y); o.w = bpack(w1.z, w1.w);
        wfrag[pair * 64 + l] = o;
    }
}

// Local exclusive scan of row-degrees (cnt>>16) -> rp, bsum.
// ALSO converts cnt -> dinv (f32, in place): dinv = rsqrt(coldeg + 1).
__global__ __launch_bounds__(SCAN_B) void k_scan1(uint32* __restrict__ cnt,
                                                  int* __restrict__ rp,
                                                  int* __restrict__ bsum, int n) {
    __shared__ int sh[SCAN_B];
    const int tid = threadIdx.x;
    const int i = blockIdx.x * SCAN_B + tid;
    uint32 cw = (i < n) ? cnt[i] : 0u;
    int v = (int)(cw >> 16);
    sh[tid] = v;
    __syncthreads();
    for (int off = 1; off < SCAN_B; off <<= 1) {
        int t = (tid >= off) ? sh[tid - off] : 0;
        __syncthreads();
        sh[tid] += t;
        __syncthreads();
    }
    if (i < n) {
        rp[i] = sh[tid] - v;                       // LOCAL exclusive
        ((float*)cnt)[i] = rsqrtf((float)((cw & 0xffffu) + 1u));
    }
    if (tid == SCAN_B - 1) bsum[blockIdx.x] = sh[SCAN_B - 1];
}

// exclusive scan of bsum in place (single block)
__global__ __launch_bounds__(SCAN_B) void k_scan2(int* __restrict__ bsum, int nb) {
    __shared__ int sh[SCAN_B];
    const int tid = threadIdx.x;
    int v = (tid < nb) ? bsum[tid] : 0;
    sh[tid] = v;
    __syncthreads();
    for (int off = 1; off < SCAN_B; off <<= 1) {
        int t = (tid >= off) ? sh[tid - off] : 0;
        __syncthreads();
        sh[tid] += t;
        __syncthreads();
    }
    if (tid < nb) bsum[tid] = sh[tid] - v;
}

// ATOMIC-FREE CSR fill: slot = rp[r] + bsum[r>>10] + rank16[e]; col only (4 B)
__global__ void k_fill(const int2* __restrict__ rows2, const int2* __restrict__ cols2,
                       const ushort* __restrict__ rank16, const int* __restrict__ rp,
                       const int* __restrict__ bsum, int* __restrict__ e4,
                       int E2, int odd,
                       const int* __restrict__ rows, const int* __restrict__ cols) {
    int t = blockIdx.x * blockDim.x + threadIdx.x;
    if (t < E2) {
        const int2 r2 = rows2[t];
        const int2 c2 = cols2[t];
        const ushort2 rk = *(const ushort2*)(rank16 + 2 * t);
        e4[rp[r2.x] + bsum[r2.x >> 10] + rk.x] = c2.x;
        e4[rp[r2.y] + bsum[r2.y >> 10] + rk.y] = c2.y;
    } else if (t == E2 && odd) {
        const int r = rows[2 * E2];
        e4[rp[r] + bsum[r >> 10] + rank16[2 * E2]] = cols[2 * E2];
    }
}

// weighted hop: out[r] = dv_r*( dv_r*x[r] + sum_c dinv[c]*x[c] )
// ONE ROW PER 64-LANE WAVE. INF32: gather f32 x (8 B/lane), else bf16 (4 B/lane).
// dinv[c] loads are wave-uniform (1 broadcast line per edge). Unroll 8,
// clamped-index + zeroed-weight tail. Output bf16x2.
template <bool INF32>
__global__ __launch_bounds__(256) void k_spmm(const void* __restrict__ xin,
                                              const int* __restrict__ rp,
                                              const int* __restrict__ bsum,
                                              const int* __restrict__ e4,
                                              const float* __restrict__ dinv,
                                              uint32* __restrict__ outh, int n, int Etot) {
    const int row = blockIdx.x * 4 + (threadIdx.x >> 6);
    if (row >= n) return;
    const int l = threadIdx.x & 63;

    const float dv = dinv[row];
    float alo, ahi;
    if (INF32) {
        const float2 sv = ((const float2*)xin)[(long long)row * 64 + l];
        alo = dv * sv.x; ahi = dv * sv.y;
    } else {
        const uint32 sv = ((const uint32*)xin)[(long long)row * 64 + l];
        alo = dv * blo(sv); ahi = dv * bhi(sv);
    }

    int e = rp[row] + bsum[row >> 10];
    const int end = (row + 1 < n) ? (rp[row + 1] + bsum[(row + 1) >> 10]) : Etot;
    while (e < end) {
        const int last = end - 1;
        int c[8];
#pragma unroll
        for (int k = 0; k < 8; ++k) {
            const int i = (e + k < last) ? e + k : last;
            c[k] = e4[i];
        }
        float w[8];
#pragma unroll
        for (int k = 0; k < 8; ++k)
            w[k] = (e + k <= last) ? dinv[c[k]] : 0.0f;
        if (INF32) {
            float2 v[8];
#pragma unroll
            for (int k = 0; k < 8; ++k)
                v[k] = ((const float2*)xin)[(long long)c[k] * 64 + l];
#pragma unroll
            for (int k = 0; k < 8; ++k) { alo += w[k] * v[k].x; ahi += w[k] * v[k].y; }
        } else {
            uint32 v[8];
#pragma unroll
            for (int k = 0; k < 8; ++k)
                v[k] = ((const uint32*)xin)[(long long)c[k] * 64 + l];
#pragma unroll
            for (int k = 0; k < 8; ++k) { alo += w[k] * blo(v[k]); ahi += w[k] * bhi(v[k]); }
        }
        e += 8;
    }

    outh[(long long)row * 64 + l] = bpack(dv * alo, dv * ahi);
}

// C[r][:] = bf16(A[r][:]) @ bf16(W)^T + b via mfma_f32_16x16x32_bf16.
// Block = 4 waves; wave = 64 rows x 64 cols (acc 64 VGPR) -> 4 blocks/CU.
// Tail waves clamp to [n-64, n): duplicate identical stores, no OOB reads.
__global__ __launch_bounds__(256, 4) void k_gemm(const short8* __restrict__ A8,
                                                 const short8* __restrict__ wfrag,
                                                 const float* __restrict__ bias,
                                                 float* __restrict__ xout, int n) {
    const int wid = threadIdx.x >> 6;
    const int rg = wid >> 1;           // row group (0/1): 64 rows each
    const int cg = wid & 1;            // col group (0/1): 64 cols each
    const int l = threadIdx.x & 63;
    const int ls = l & 15;
    const int lg = l >> 4;
    long long row0 = (long long)blockIdx.x * 128 + rg * 64;
    if (row0 + 64 > n) row0 = (long long)n - 64;

    float breg[4];
#pragma unroll
    for (int jt = 0; jt < 4; ++jt) breg[jt] = bias[cg * 64 + jt * 16 + ls];

    f32x4 acc[4][4] = {};

#pragma unroll
    for (int kq = 0; kq < 4; ++kq) {
        short8 af[4];
#pragma unroll
        for (int m = 0; m < 4; ++m)
            af[m] = A8[(row0 + m * 16 + ls) * 16 + kq * 4 + lg];
#pragma unroll
        for (int jt = 0; jt < 4; ++jt) {
            const short8 bf = wfrag[(kq * 8 + cg * 4 + jt) * 64 + l];
#pragma unroll
            for (int m = 0; m < 4; ++m)
                acc[m][jt] = __builtin_amdgcn_mfma_f32_16x16x32_bf16(
                    af[m], bf, acc[m][jt], 0, 0, 0);
        }
    }

#pragma unroll
    for (int m = 0; m < 4; ++m) {
#pragma unroll
        for (int q = 0; q < 4; ++q) {
            const long long row = row0 + m * 16 + lg * 4 + q;
            float* orow = xout + (row << 7) + cg * 64;
#pragma unroll
            for (int jt = 0; jt < 4; ++jt)
                orow[jt * 16 + ls] = acc[m][jt][q] + breg[jt];
        }
    }
}

extern "C" void kernel_launch(void* const* d_in, const int* in_sizes, int n_in,
                              void* d_out, int out_size, void* d_ws, size_t ws_size,
                              hipStream_t stream) {
    const float* x = (const float*)d_in[0];
    const int* ei = (const int*)d_in[1];
    const float* Wm = (const float*)d_in[2];
    const float* bias = (const float*)d_in[3];
    float* out = (float*)d_out;

    const int n = in_sizes[0] / D;
    const int E = in_sizes[1] / 2;
    const int E2 = E >> 1;
    const int odd = E & 1;
    const int NB = (n + SCAN_B - 1) / SCAN_B;

    char* ws = (char*)d_ws;
    size_t off = 0;
    auto alloc = [&](long long bytes) {
        void* p = ws + off;
        off += (size_t)((bytes + 511) & ~511LL);
        return p;
    };
    uint32* cnt   = (uint32*)alloc((long long)n * 4);   // packed hist -> dinv (f32) in place
    int* rp       = (int*)alloc((long long)n * 4);      // LOCAL exclusive row offsets
    int* bsum     = (int*)alloc((long long)SCAN_B * 4); // scanned block bases
    ushort* rank16= (ushort*)alloc((long long)E * 2);   // per-edge row rank
    int* e4       = (int*)alloc((long long)E * 4);      // CSR col only
    uint4* y1h    = (uint4*)alloc((long long)n * 256);  // bf16 hop-1 output
    uint4* y2h    = (uint4*)alloc((long long)n * 256);  // bf16 hop-2 output
    uint4* wfrag  = (uint4*)alloc(2048LL * 16);         // 32 KB B-fragments
    float* dinv   = (float*)cnt;

    const int* rows = ei;
    const int* cols = ei + E;
    const int2* rows2 = (const int2*)rows;
    const int2* cols2 = (const int2*)cols;

    const int B = 256;
    const int ncount = ceil_div_ll(E2 + 1, B);

    hipMemsetAsync(cnt, 0, (size_t)n * 4, stream);
    // count (atomic-bound, emits ranks) + wprep — no cvt anywhere
    k_fused<<<ncount + 8, B, 0, stream>>>(
        rows2, cols2, cnt, rank16, E2, odd, rows, cols, Wm, wfrag, ncount);

    k_scan1<<<NB, SCAN_B, 0, stream>>>(cnt, rp, bsum, n);    // + cnt -> dinv in place
    k_scan2<<<1, SCAN_B, 0, stream>>>(bsum, NB);
    k_fill<<<ceil_div_ll(E2 + 1, B), B, 0, stream>>>(
        rows2, cols2, rank16, rp, bsum, e4, E2, odd, rows, cols);

    // hop 1: f32 gathers from x -> bf16 y1 ; hop 2: bf16 gathers -> bf16 y2
    k_spmm<true><<<ceil_div_ll(n, 4), B, 0, stream>>>(
        (const void*)x, rp, bsum, e4, dinv, (uint32*)y1h, n, E);
    k_spmm<false><<<ceil_div_ll(n, 4), B, 0, stream>>>(
        (const void*)y1h, rp, bsum, e4, dinv, (uint32*)y2h, n, E);

    k_gemm<<<ceil_div_ll(n, 128), B, 0, stream>>>(
        (const short8*)y2h, (const short8*)wfrag, bias, out, n);
}

// Round 15
// 179.340 us; speedup vs baseline: 1.1184x; 1.1184x over previous
//
#include <hip/hip_runtime.h>

#define D 128
#define SCAN_B 1024

static inline int ceil_div_ll(long long a, int b) { return (int)((a + b - 1) / b); }

typedef unsigned int uint32;
typedef __attribute__((ext_vector_type(8))) short short8;   // 8 x bf16 (4 VGPRs)
typedef __attribute__((ext_vector_type(4))) float f32x4;    // MFMA C/D

__device__ __forceinline__ float blo(uint32 u) { return __uint_as_float(u << 16); }
__device__ __forceinline__ float bhi(uint32 u) { return __uint_as_float(u & 0xffff0000u); }
__device__ __forceinline__ uint32 bpack(float a, float b) {   // 2x f32 -> bf16x2 RTNE
    uint32 ua = __float_as_uint(a), ub = __float_as_uint(b);
    ua += 0x7fffu + ((ua >> 16) & 1u);
    ub += 0x7fffu + ((ub >> 16) & 1u);
    return (ua >> 16) | (ub & 0xffff0000u);
}

// FUSED, roles INTERLEAVED (1 count : 5 cvt per 6 blocks, cvt remainder, 8 wprep).
// Count emits per-edge row-rank so CSR fill needs no atomics. The interleave
// is load-bearing: count-only runs SLOWER (r14: 65-69 vs 58.8 us).
__global__ __launch_bounds__(256) void k_fused(
        const int2* __restrict__ rows2, const int2* __restrict__ cols2,
        uint32* __restrict__ cnt, ushort* __restrict__ rank16, int E2, int odd,
        const int* __restrict__ rows, const int* __restrict__ cols,
        const float4* __restrict__ x, uint4* __restrict__ xh, long long totcvt,
        const float* __restrict__ Wm, uint4* __restrict__ wfrag,
        int ncount, int ncvt, int cvtLeft) {
    const int b = blockIdx.x;
    int role, idx;
    if (b < 6 * ncount) {
        const int g = b / 6, p = b - g * 6;
        if (p == 0) { role = 0; idx = g; }
        else        { role = 1; idx = g * 5 + (p - 1); }
    } else if (b < 6 * ncount + cvtLeft) {
        role = 1; idx = 5 * ncount + (b - 6 * ncount);
    } else {
        role = 2; idx = b - 6 * ncount - cvtLeft;
    }

    if (role == 0) {
        const int t = idx * 256 + threadIdx.x;
        if (t < E2) {
            const int2 r2 = rows2[t];
            const int2 c2 = cols2[t];
            const uint32 o0 = atomicAdd(&cnt[r2.x], 0x10000u);
            atomicAdd(&cnt[c2.x], 1u);
            const uint32 o1 = atomicAdd(&cnt[r2.y], 0x10000u);
            atomicAdd(&cnt[c2.y], 1u);
            ushort2 rk;
            rk.x = (ushort)(o0 >> 16);
            rk.y = (ushort)(o1 >> 16);
            *(ushort2*)(rank16 + 2 * t) = rk;
        } else if (t == E2 && odd) {
            const uint32 o = atomicAdd(&cnt[rows[2 * E2]], 0x10000u);
            atomicAdd(&cnt[cols[2 * E2]], 1u);
            rank16[2 * E2] = (ushort)(o >> 16);
        }
    } else if (role == 1) {
        if (idx >= ncvt) return;
        const long long i = (long long)idx * 256 + threadIdx.x;
        if (i < totcvt) {
            const float4 a = x[i * 2];
            const float4 c = x[i * 2 + 1];
            uint4 o;
            o.x = bpack(a.x, a.y); o.y = bpack(a.z, a.w);
            o.z = bpack(c.x, c.y); o.w = bpack(c.z, c.w);
            xh[i] = o;
        }
    } else {
        // wprep: lane l of entry (kq*8+jt) holds W[jt*16+(l&15)][kq*32+(l>>4)*8..+7]
        const int t = idx * 256 + threadIdx.x;
        if (t >= 2048) return;
        const int l = t & 63;
        const int pair = t >> 6;
        const int kq = pair >> 3;
        const int jt = pair & 7;
        const int s = l & 15;
        const int g = l >> 4;
        const float* src = Wm + ((long long)(jt * 16 + s) << 7) + kq * 32 + g * 8;
        const float4 w0 = *(const float4*)(src);
        const float4 w1 = *(const float4*)(src + 4);
        uint4 o;
        o.x = bpack(w0.x, w0.y); o.y = bpack(w0.z, w0.w);
        o.z = bpack(w1.x, w1.y); o.w = bpack(w1.z, w1.w);
        wfrag[pair * 64 + l] = o;
    }
}

// Local exclusive scan of row-degrees (cnt>>16) -> rp, bsum.
// ALSO converts cnt -> dinv (f32, in place): dinv = rsqrt(coldeg + 1).
__global__ __launch_bounds__(SCAN_B) void k_scan1(uint32* __restrict__ cnt,
                                                  int* __restrict__ rp,
                                                  int* __restrict__ bsum, int n) {
    __shared__ int sh[SCAN_B];
    const int tid = threadIdx.x;
    const int i = blockIdx.x * SCAN_B + tid;
    uint32 cw = (i < n) ? cnt[i] : 0u;
    int v = (int)(cw >> 16);
    sh[tid] = v;
    __syncthreads();
    for (int off = 1; off < SCAN_B; off <<= 1) {
        int t = (tid >= off) ? sh[tid - off] : 0;
        __syncthreads();
        sh[tid] += t;
        __syncthreads();
    }
    if (i < n) {
        rp[i] = sh[tid] - v;                       // LOCAL exclusive
        ((float*)cnt)[i] = rsqrtf((float)((cw & 0xffffu) + 1u));
    }
    if (tid == SCAN_B - 1) bsum[blockIdx.x] = sh[SCAN_B - 1];
}

// exclusive scan of bsum in place (single block)
__global__ __launch_bounds__(SCAN_B) void k_scan2(int* __restrict__ bsum, int nb) {
    __shared__ int sh[SCAN_B];
    const int tid = threadIdx.x;
    int v = (tid < nb) ? bsum[tid] : 0;
    sh[tid] = v;
    __syncthreads();
    for (int off = 1; off < SCAN_B; off <<= 1) {
        int t = (tid >= off) ? sh[tid - off] : 0;
        __syncthreads();
        sh[tid] += t;
        __syncthreads();
    }
    if (tid < nb) bsum[tid] = sh[tid] - v;
}

// ATOMIC-FREE CSR fill: slot = rp[r] + bsum[r>>10] + rank16[e]; col only (4 B)
__global__ void k_fill(const int2* __restrict__ rows2, const int2* __restrict__ cols2,
                       const ushort* __restrict__ rank16, const int* __restrict__ rp,
                       const int* __restrict__ bsum, int* __restrict__ e4,
                       int E2, int odd,
                       const int* __restrict__ rows, const int* __restrict__ cols) {
    int t = blockIdx.x * blockDim.x + threadIdx.x;
    if (t < E2) {
        const int2 r2 = rows2[t];
        const int2 c2 = cols2[t];
        const ushort2 rk = *(const ushort2*)(rank16 + 2 * t);
        e4[rp[r2.x] + bsum[r2.x >> 10] + rk.x] = c2.x;
        e4[rp[r2.y] + bsum[r2.y >> 10] + rk.y] = c2.y;
    } else if (t == E2 && odd) {
        const int r = rows[2 * E2];
        e4[rp[r] + bsum[r >> 10] + rank16[2 * E2]] = cols[2 * E2];
    }
}

// weighted hop on bf16: out[r] = dv_r*( dv_r*xh[r] + sum_c dinv[c]*xh[c] )
// ONE ROW PER 64-LANE WAVE, 4 B (bf16x2)/lane payload gathers.
// dinv[c] loads are wave-uniform broadcasts (L2-resident 400 KB array).
// Unroll 8 with clamped-index + zeroed-weight tail. Output bf16x2.
__global__ __launch_bounds__(256) void k_spmm(const uint32* __restrict__ xh,
                                              const int* __restrict__ rp,
                                              const int* __restrict__ bsum,
                                              const int* __restrict__ e4,
                                              const float* __restrict__ dinv,
                                              uint32* __restrict__ outh, int n, int Etot) {
    const int row = blockIdx.x * 4 + (threadIdx.x >> 6);
    if (row >= n) return;
    const int l = threadIdx.x & 63;

    const float dv = dinv[row];
    const uint32 sv = xh[(long long)row * 64 + l];
    float alo = dv * blo(sv);
    float ahi = dv * bhi(sv);

    int e = rp[row] + bsum[row >> 10];
    const int end = (row + 1 < n) ? (rp[row + 1] + bsum[(row + 1) >> 10]) : Etot;
    while (e < end) {
        const int last = end - 1;
        int c[8];
#pragma unroll
        for (int k = 0; k < 8; ++k) {
            const int i = (e + k < last) ? e + k : last;
            c[k] = e4[i];
        }
        float w[8];
#pragma unroll
        for (int k = 0; k < 8; ++k)
            w[k] = (e + k <= last) ? dinv[c[k]] : 0.0f;
        uint32 v[8];
#pragma unroll
        for (int k = 0; k < 8; ++k) v[k] = xh[(long long)c[k] * 64 + l];
#pragma unroll
        for (int k = 0; k < 8; ++k) { alo += w[k] * blo(v[k]); ahi += w[k] * bhi(v[k]); }
        e += 8;
    }

    outh[(long long)row * 64 + l] = bpack(dv * alo, dv * ahi);
}

// C[r][:] = bf16(A[r][:]) @ bf16(W)^T + b via mfma_f32_16x16x32_bf16.
// Block = 4 waves; wave = 64 rows x 64 cols (acc 64 VGPR) -> 4 blocks/CU.
// Tail waves clamp to [n-64, n): duplicate identical stores, no OOB reads.
__global__ __launch_bounds__(256, 4) void k_gemm(const short8* __restrict__ A8,
                                                 const short8* __restrict__ wfrag,
                                                 const float* __restrict__ bias,
                                                 float* __restrict__ xout, int n) {
    const int wid = threadIdx.x >> 6;
    const int rg = wid >> 1;           // row group (0/1): 64 rows each
    const int cg = wid & 1;            // col group (0/1): 64 cols each
    const int l = threadIdx.x & 63;
    const int ls = l & 15;
    const int lg = l >> 4;
    long long row0 = (long long)blockIdx.x * 128 + rg * 64;
    if (row0 + 64 > n) row0 = (long long)n - 64;

    float breg[4];
#pragma unroll
    for (int jt = 0; jt < 4; ++jt) breg[jt] = bias[cg * 64 + jt * 16 + ls];

    f32x4 acc[4][4] = {};

#pragma unroll
    for (int kq = 0; kq < 4; ++kq) {
        short8 af[4];
#pragma unroll
        for (int m = 0; m < 4; ++m)
            af[m] = A8[(row0 + m * 16 + ls) * 16 + kq * 4 + lg];
#pragma unroll
        for (int jt = 0; jt < 4; ++jt) {
            const short8 bf = wfrag[(kq * 8 + cg * 4 + jt) * 64 + l];
#pragma unroll
            for (int m = 0; m < 4; ++m)
                acc[m][jt] = __builtin_amdgcn_mfma_f32_16x16x32_bf16(
                    af[m], bf, acc[m][jt], 0, 0, 0);
        }
    }

#pragma unroll
    for (int m = 0; m < 4; ++m) {
#pragma unroll
        for (int q = 0; q < 4; ++q) {
            const long long row = row0 + m * 16 + lg * 4 + q;
            float* orow = xout + (row << 7) + cg * 64;
#pragma unroll
            for (int jt = 0; jt < 4; ++jt)
                orow[jt * 16 + ls] = acc[m][jt][q] + breg[jt];
        }
    }
}

extern "C" void kernel_launch(void* const* d_in, const int* in_sizes, int n_in,
                              void* d_out, int out_size, void* d_ws, size_t ws_size,
                              hipStream_t stream) {
    const float* x = (const float*)d_in[0];
    const int* ei = (const int*)d_in[1];
    const float* Wm = (const float*)d_in[2];
    const float* bias = (const float*)d_in[3];
    float* out = (float*)d_out;

    const int n = in_sizes[0] / D;
    const int E = in_sizes[1] / 2;
    const int E2 = E >> 1;
    const int odd = E & 1;
    const int NB = (n + SCAN_B - 1) / SCAN_B;

    char* ws = (char*)d_ws;
    size_t off = 0;
    auto alloc = [&](long long bytes) {
        void* p = ws + off;
        off += (size_t)((bytes + 511) & ~511LL);
        return p;
    };
    uint32* cnt   = (uint32*)alloc((long long)n * 4);   // packed hist -> dinv (f32) in place
    int* rp       = (int*)alloc((long long)n * 4);      // LOCAL exclusive row offsets
    int* bsum     = (int*)alloc((long long)SCAN_B * 4); // scanned block bases
    ushort* rank16= (ushort*)alloc((long long)E * 2);   // per-edge row rank
    int* e4       = (int*)alloc((long long)E * 4);      // CSR col only
    uint4* xh     = (uint4*)alloc((long long)n * 256);  // bf16 x; reused as hop-2 output
    uint4* y1h    = (uint4*)alloc((long long)n * 256);  // bf16 hop-1 output
    uint4* wfrag  = (uint4*)alloc(2048LL * 16);         // 32 KB B-fragments
    float* dinv   = (float*)cnt;

    const int* rows = ei;
    const int* cols = ei + E;
    const int2* rows2 = (const int2*)rows;
    const int2* cols2 = (const int2*)cols;

    const int B = 256;
    const long long totcvt = (long long)n * 16;         // uint4s
    const int ncount = ceil_div_ll(E2 + 1, B);
    const int ncvt = ceil_div_ll(totcvt, B);
    const int cvtLeft = (ncvt > 5 * ncount) ? (ncvt - 5 * ncount) : 0;
    const int grid_fused = 6 * ncount + cvtLeft + 8;

    hipMemsetAsync(cnt, 0, (size_t)n * 4, stream);
    // count (atomic-bound, emits ranks) || cvt || wprep — interleaved (load-bearing)
    k_fused<<<grid_fused, B, 0, stream>>>(
        rows2, cols2, cnt, rank16, E2, odd, rows, cols,
        (const float4*)x, xh, totcvt, Wm, wfrag, ncount, ncvt, cvtLeft);

    k_scan1<<<NB, SCAN_B, 0, stream>>>(cnt, rp, bsum, n);    // + cnt -> dinv in place
    k_scan2<<<1, SCAN_B, 0, stream>>>(bsum, NB);
    k_fill<<<ceil_div_ll(E2 + 1, B), B, 0, stream>>>(
        rows2, cols2, rank16, rp, bsum, e4, E2, odd, rows, cols);

    // hop 1: y1 = Anorm @ xh ; hop 2: xh = Anorm @ y1 (xh dead after hop 1)
    k_spmm<<<ceil_div_ll(n, 4), B, 0, stream>>>(
        (const uint32*)xh, rp, bsum, e4, dinv, (uint32*)y1h, n, E);
    k_spmm<<<ceil_div_ll(n, 4), B, 0, stream>>>(
        (const uint32*)y1h, rp, bsum, e4, dinv, (uint32*)xh, n, E);

    k_gemm<<<ceil_div_ll(n, 128), B, 0, stream>>>(
        (const short8*)xh, (const short8*)wfrag, bias, out, n);
}